// Round 3
// baseline (8815.746 us; speedup 1.0000x reference)
//
#include <hip/hip_runtime.h>

typedef unsigned short u16;
typedef __attribute__((ext_vector_type(8))) short s16x8;
typedef __attribute__((ext_vector_type(4))) float f32x4;

#define T_ 64
#define B_ 48
#define H_ 1152
#define E_ 400
#define EPAD 416
#define V_ 32000
#define FOURH 4608
#define TB_ 3072
#define HB (B_*H_)            /* 55296 */
#define LSTRIDE (65*HB)       /* per-layer slot stride in H history */
#define RBLK 256              /* persistent recurrence block count (1/CU) */

/* ---- workspace byte offsets (all 256-aligned) ---- */
#define OFF_ZPRE  ((size_t)0)          /* f32 [3072][4608] = 56,623,104 B (reused per layer) */
#define OFF_HHI   ((size_t)56623104)   /* u16 [3][65][48][1152] = 21,565,440 B */
#define OFF_HLO   ((size_t)78188544)   /* u16 same */
#define OFF_CST   ((size_t)99753984)   /* f32 [3][48][1152] = 663,552 B */
#define OFF_ZH    ((size_t)100417536)  /* u16 [3072][416] = 2,555,904 B */
#define OFF_ZL    ((size_t)102973440)  /* u16 same */
#define OFF_P0    ((size_t)105529344)  /* f32 2 x [48][4608] = 1,769,472 B */
#define OFF_CTR   ((size_t)116146176)  /* int[256] barrier/counters */

__device__ __forceinline__ u16 f2bf(float x) {
    unsigned u = __float_as_uint(x);
    u += 0x7fffu + ((u >> 16) & 1u);      // round-to-nearest-even
    return (u16)(u >> 16);
}
__device__ __forceinline__ float bf2f(u16 h) {
    return __uint_as_float(((unsigned)h) << 16);
}
__device__ __forceinline__ void split8(const float* p, s16x8& hi, s16x8& lo) {
    f32x4 a = *(const f32x4*)(p);
    f32x4 b = *(const f32x4*)(p + 4);
    float v[8];
#pragma unroll
    for (int j = 0; j < 4; ++j) { v[j] = a[j]; v[j + 4] = b[j]; }
#pragma unroll
    for (int j = 0; j < 8; ++j) {
        u16 h = f2bf(v[j]);
        hi[j] = (short)h;
        lo[j] = (short)f2bf(v[j] - bf2f(h));
    }
}
__device__ __forceinline__ void split8r(f32x4 a, f32x4 b, s16x8& hi, s16x8& lo) {
    float v[8];
#pragma unroll
    for (int j = 0; j < 4; ++j) { v[j] = a[j]; v[j + 4] = b[j]; }
#pragma unroll
    for (int j = 0; j < 8; ++j) {
        u16 h = f2bf(v[j]);
        hi[j] = (short)h;
        lo[j] = (short)f2bf(v[j] - bf2f(h));
    }
}
__device__ __forceinline__ f32x4 mfma16(s16x8 a, s16x8 b, f32x4 c) {
    return __builtin_amdgcn_mfma_f32_16x16x32_bf16(a, b, c, 0, 0, 0);
}

/* ---- agent-coherent (sc1, L1/L2-bypass) accessors for cross-block state.
   Keeps the read-only weight slice L2-resident: no cache-wide flush ever. ---- */
__device__ __forceinline__ float ld_sc(const float* p) {
    return __hip_atomic_load(p, __ATOMIC_RELAXED, __HIP_MEMORY_SCOPE_AGENT);
}
__device__ __forceinline__ void st_sc(float* p, float v) {
    __hip_atomic_store(p, v, __ATOMIC_RELAXED, __HIP_MEMORY_SCOPE_AGENT);
}
__device__ __forceinline__ void st_sc16(u16* p, u16 v) {
    __hip_atomic_store(p, v, __ATOMIC_RELAXED, __HIP_MEMORY_SCOPE_AGENT);
}

/* ---------------- two-level device-scope grid barrier (256 blocks: 16x16) ---- */
__device__ __forceinline__ void grid_barrier(int* ctrs, int nblk) {
    asm volatile("s_waitcnt vmcnt(0)" ::: "memory");  // release: sc1 stores at IF
    __syncthreads();
    if (threadIdx.x == 0) {
        int* gen = ctrs + 252;
        int* root = ctrs + 248;
        int* gcnt = ctrs + ((blockIdx.x & 15) << 4);
        const int gsz = nblk >> 4;
        int g = __hip_atomic_load(gen, __ATOMIC_RELAXED, __HIP_MEMORY_SCOPE_AGENT);
        int old = __hip_atomic_fetch_add(gcnt, 1, __ATOMIC_RELAXED, __HIP_MEMORY_SCOPE_AGENT);
        if (old == gsz - 1) {
            __hip_atomic_store(gcnt, 0, __ATOMIC_RELAXED, __HIP_MEMORY_SCOPE_AGENT);
            asm volatile("s_waitcnt vmcnt(0)" ::: "memory");
            int r = __hip_atomic_fetch_add(root, 1, __ATOMIC_RELAXED, __HIP_MEMORY_SCOPE_AGENT);
            if (r == 15) {
                __hip_atomic_store(root, 0, __ATOMIC_RELAXED, __HIP_MEMORY_SCOPE_AGENT);
                asm volatile("s_waitcnt vmcnt(0)" ::: "memory");
                __hip_atomic_fetch_add(gen, 1, __ATOMIC_RELAXED, __HIP_MEMORY_SCOPE_AGENT);
            }
        }
        while (__hip_atomic_load(gen, __ATOMIC_RELAXED, __HIP_MEMORY_SCOPE_AGENT) == g) {
            __builtin_amdgcn_s_sleep(2);
        }
    }
    __syncthreads();
}

/* ---------------- embedding gather + bf16 hi/lo split ---------------- */
__global__ void gather_split_kernel(const int* __restrict__ x, const float* __restrict__ embW,
                                    u16* __restrict__ Zh, u16* __restrict__ Zl) {
    int i = blockIdx.x * blockDim.x + threadIdx.x;
    const int total = TB_ * EPAD;
    if (i >= total) return;
    int tb = i / EPAD, k = i - tb * EPAD;
    float v = 0.f;
    if (k < E_) v = embW[(size_t)x[tb] * E_ + k];
    u16 h = f2bf(v);
    Zh[i] = h;
    Zl[i] = f2bf(v - bf2f(h));
}

/* ---------------- init h0/c0 into state buffers ---------------- */
__global__ void init_state_kernel(const float* __restrict__ h0, const float* __restrict__ c0,
                                  u16* __restrict__ Hhi, u16* __restrict__ Hlo,
                                  float* __restrict__ Cst) {
    int i = blockIdx.x * blockDim.x + threadIdx.x;
    if (i >= 3 * HB) return;
    int l = i / HB, r = i - l * HB;
    float h = h0[i];
    u16 hh = f2bf(h);
    size_t idx = (size_t)l * LSTRIDE + r;   // slot 0 = t=-1 state
    Hhi[idx] = hh;
    Hlo[idx] = f2bf(h - bf2f(hh));
    Cst[i] = c0[i];
}

/* ---------------- generic big GEMM (phase A, Zpre1/2, decode) ---------------- */
__global__ __launch_bounds__(256, 2) void gemm_bias_kernel(
    const u16* __restrict__ Ahi, const u16* __restrict__ Alo, int lda,
    const float* __restrict__ W, int ldw, int kvalid, int ksteps,
    const float* __restrict__ bias1, const float* __restrict__ bias2,
    float* __restrict__ C, int ldc) {
    const int lane = threadIdx.x & 63;
    const int wv = threadIdx.x >> 6;
    const int m16 = lane & 15, q = lane >> 4;
    const int mbase = blockIdx.y * 192 + wv * 48;
    const int nbase = blockIdx.x * 128;

    f32x4 acc[8][3];
#pragma unroll
    for (int s8 = 0; s8 < 8; ++s8)
#pragma unroll
        for (int mt = 0; mt < 3; ++mt) acc[s8][mt] = (f32x4){0.f, 0.f, 0.f, 0.f};

    const u16* arow[3];
    const u16* alrow[3];
#pragma unroll
    for (int mt = 0; mt < 3; ++mt) {
        size_t m = (size_t)(mbase + mt * 16 + m16);
        arow[mt] = Ahi + m * lda + q * 8;
        alrow[mt] = Alo + m * lda + q * 8;
    }
    const float* wrow[8];
#pragma unroll
    for (int s8 = 0; s8 < 8; ++s8) {
        size_t n = (size_t)(nbase + s8 * 16 + m16);
        wrow[s8] = W + n * ldw + q * 8;
    }

    for (int ks = 0; ks < ksteps; ++ks) {
        int k = ks * 32;
        s16x8 ah[3], al[3];
#pragma unroll
        for (int mt = 0; mt < 3; ++mt) {
            ah[mt] = *(const s16x8*)(arow[mt] + k);
            al[mt] = *(const s16x8*)(alrow[mt] + k);
        }
        int kk = k + q * 8;
#pragma unroll
        for (int s8 = 0; s8 < 8; ++s8) {
            s16x8 wh, wl;
            if (kk + 8 <= kvalid) {
                split8(wrow[s8] + k, wh, wl);
            } else {
#pragma unroll
                for (int j = 0; j < 8; ++j) { wh[j] = 0; wl[j] = 0; }
            }
#pragma unroll
            for (int mt = 0; mt < 3; ++mt) {
                acc[s8][mt] = mfma16(ah[mt], wh, acc[s8][mt]);
                acc[s8][mt] = mfma16(ah[mt], wl, acc[s8][mt]);
                acc[s8][mt] = mfma16(al[mt], wh, acc[s8][mt]);
            }
        }
    }
    /* epilogue */
#pragma unroll
    for (int s8 = 0; s8 < 8; ++s8) {
        int n = nbase + s8 * 16 + m16;
        float bv = (bias1 ? bias1[n] : 0.f) + (bias2 ? bias2[n] : 0.f);
#pragma unroll
        for (int mt = 0; mt < 3; ++mt)
#pragma unroll
            for (int r = 0; r < 4; ++r) {
                int m = mbase + mt * 16 + q * 4 + r;
                C[(size_t)m * ldc + n] = acc[s8][mt][r] + bv;
            }
    }
}

/* ---------------- persistent single-layer LSTM recurrence ----------------
   64 stages of: h-GEMM (pre += h_{t-1} Wh^T, z-part pre-added from Zpre) then
   gates. XCD-pinned N-strips: wave's strip has strip%8 == blk&7 and is FIXED
   across all stages, so each XCD re-reads only its 2.65 MB weight slice ->
   L2-resident (barrier never flushes; all mutable state goes sc1/IF).
   Task coverage is a bijection regardless of physical block->XCD mapping. */
__global__ __launch_bounds__(256, 2) void recur_layer_kernel(
    const float* __restrict__ W,               /* Wh_l [4608][1152] */
    const float* __restrict__ bi, const float* __restrict__ bh,
    const float* __restrict__ Zpre,            /* [64*48][4608] z-part+Wi*x */
    u16* __restrict__ Hhi, u16* __restrict__ Hlo,  /* layer base [65][48][1152] */
    float* __restrict__ Cst,                   /* [48][1152] */
    float* __restrict__ P0, float* __restrict__ P1,  /* [48][4608] each */
    int* __restrict__ ctrs,
    float* __restrict__ outh, float* __restrict__ outc) {
    const int lane = threadIdx.x & 63;
    const int slot = threadIdx.x >> 6;
    const int blk = blockIdx.x;
    const int m16 = lane & 15, q = lane >> 4;
    const int xg = blk & 7;                    /* XCD group (round-robin dispatch) */
    const int li = ((blk >> 3) << 2) + slot;   /* 0..127 within group */
    const bool havetask = (li < 72);           /* 36 strips x 2 k-halves */
    const int strip = (li >> 1) * 8 + xg;      /* fixed strip across all stages */
    const int kh = li & 1;
    const int n0 = strip * 16;
    const int koff = kh * 576;
    const float* wrow = W + (size_t)(n0 + m16) * H_ + koff + q * 8;
    float* Pout = kh ? P1 : P0;
    const int gi = blk * 256 + (int)threadIdx.x;   /* gates item (216 blocks cover HB) */
    const int gb = gi / H_, gj = gi - gb * H_;

    for (int t = 0; t < 64; ++t) {
        /* ---- GEMM phase ---- */
        if (havetask) {
            float zin[3][4];
            if (kh == 0) {
                const float* zp = Zpre + (size_t)(t * B_) * FOURH + n0 + m16;
#pragma unroll
                for (int mt = 0; mt < 3; ++mt)
#pragma unroll
                    for (int r = 0; r < 4; ++r)
                        zin[mt][r] = ld_sc(zp + (size_t)(mt * 16 + q * 4 + r) * FOURH);
            } else {
#pragma unroll
                for (int mt = 0; mt < 3; ++mt)
#pragma unroll
                    for (int r = 0; r < 4; ++r) zin[mt][r] = 0.f;
            }
            f32x4 acc[3];
#pragma unroll
            for (int mt = 0; mt < 3; ++mt) acc[mt] = (f32x4){0.f, 0.f, 0.f, 0.f};
            const u16* arow[3];
            const u16* alrow[3];
#pragma unroll
            for (int mt = 0; mt < 3; ++mt) {
                size_t ro = (size_t)t * HB + (size_t)(mt * 16 + m16) * H_ + koff + q * 8;
                arow[mt] = Hhi + ro;
                alrow[mt] = Hlo + ro;
            }
            /* software pipeline: weights depth-2 (L2-hit), A depth-1 */
            f32x4 w0A = *(const f32x4*)(wrow);
            f32x4 w0B = *(const f32x4*)(wrow + 4);
            f32x4 w1A = *(const f32x4*)(wrow + 32);
            f32x4 w1B = *(const f32x4*)(wrow + 36);
            s16x8 ah[3], al[3];
#pragma unroll
            for (int mt = 0; mt < 3; ++mt) {
                ah[mt] = *(const s16x8*)(arow[mt]);
                al[mt] = *(const s16x8*)(alrow[mt]);
            }
#pragma unroll 2
            for (int ks = 0; ks < 18; ++ks) {
                int kp1 = ks + 1; if (kp1 > 17) kp1 = 17;
                int kp2 = ks + 2; if (kp2 > 17) kp2 = 17;
                const int kn1 = kp1 * 32, kn2 = kp2 * 32;
                f32x4 w2A = *(const f32x4*)(wrow + kn2);
                f32x4 w2B = *(const f32x4*)(wrow + kn2 + 4);
                s16x8 nah[3], nal[3];
#pragma unroll
                for (int mt = 0; mt < 3; ++mt) {
                    nah[mt] = *(const s16x8*)(arow[mt] + kn1);
                    nal[mt] = *(const s16x8*)(alrow[mt] + kn1);
                }
                s16x8 wh, wl;
                split8r(w0A, w0B, wh, wl);
#pragma unroll
                for (int mt = 0; mt < 3; ++mt) {
                    acc[mt] = mfma16(ah[mt], wh, acc[mt]);
                    acc[mt] = mfma16(ah[mt], wl, acc[mt]);
                    acc[mt] = mfma16(al[mt], wh, acc[mt]);
                }
                w0A = w1A; w0B = w1B; w1A = w2A; w1B = w2B;
#pragma unroll
                for (int mt = 0; mt < 3; ++mt) { ah[mt] = nah[mt]; al[mt] = nal[mt]; }
            }
            float* pout = Pout + n0 + m16;
#pragma unroll
            for (int mt = 0; mt < 3; ++mt)
#pragma unroll
                for (int r = 0; r < 4; ++r)
                    st_sc(pout + (size_t)(mt * 16 + q * 4 + r) * FOURH,
                          acc[mt][r] + zin[mt][r]);
        }
        grid_barrier(ctrs, RBLK);

        /* ---- gates phase: pre = P0 + P1 + bi + bh ---- */
        if (gi < HB) {
            const float* p0 = P0 + (size_t)gb * FOURH;
            const float* p1 = P1 + (size_t)gb * FOURH;
            float pi = ld_sc(p0 + gj) + ld_sc(p1 + gj) + bi[gj] + bh[gj];
            float pf = ld_sc(p0 + H_ + gj) + ld_sc(p1 + H_ + gj) + bi[H_ + gj] + bh[H_ + gj];
            float po = ld_sc(p0 + 2 * H_ + gj) + ld_sc(p1 + 2 * H_ + gj) + bi[2 * H_ + gj] + bh[2 * H_ + gj];
            float pg = ld_sc(p0 + 3 * H_ + gj) + ld_sc(p1 + 3 * H_ + gj) + bi[3 * H_ + gj] + bh[3 * H_ + gj];
            float c = ld_sc(Cst + gi);
            float ig = 1.f / (1.f + expf(-pi));
            float fg = 1.f / (1.f + expf(-pf));
            float og = 1.f / (1.f + expf(-po));
            float gg = tanhf(pg);
            float cn = fg * c + ig * gg;
            float hn = og * tanhf(cn);
            st_sc(Cst + gi, cn);
            u16 hh = f2bf(hn);
            size_t hidx = (size_t)(t + 1) * HB + gi;
            st_sc16(Hhi + hidx, hh);
            st_sc16(Hlo + hidx, f2bf(hn - bf2f(hh)));
            if (t == 63) {
                outh[gi] = hn;
                outc[gi] = cn;
            }
        }
        grid_barrier(ctrs, RBLK);
    }
}

extern "C" void kernel_launch(void* const* d_in, const int* in_sizes, int n_in,
                              void* d_out, int out_size, void* d_ws, size_t ws_size,
                              hipStream_t stream) {
    (void)in_sizes; (void)n_in; (void)out_size; (void)ws_size;
    const int* x = (const int*)d_in[0];
    const float* h0 = (const float*)d_in[1];
    const float* c0 = (const float*)d_in[2];
    const float* embW = (const float*)d_in[3];
    const float* Wi0 = (const float*)d_in[4];
    const float* bi0 = (const float*)d_in[5];
    const float* Wh0 = (const float*)d_in[6];
    const float* bh0 = (const float*)d_in[7];
    const float* Wi1 = (const float*)d_in[8];
    const float* bi1 = (const float*)d_in[9];
    const float* Wh1 = (const float*)d_in[10];
    const float* bh1 = (const float*)d_in[11];
    const float* Wi2 = (const float*)d_in[12];
    const float* bi2 = (const float*)d_in[13];
    const float* Wh2 = (const float*)d_in[14];
    const float* bh2 = (const float*)d_in[15];
    const float* Wdec = (const float*)d_in[16];
    const float* bdec = (const float*)d_in[17];

    char* ws = (char*)d_ws;
    float* Zpre = (float*)(ws + OFF_ZPRE);
    u16* Hhi = (u16*)(ws + OFF_HHI);
    u16* Hlo = (u16*)(ws + OFF_HLO);
    float* Cst = (float*)(ws + OFF_CST);
    u16* Zh = (u16*)(ws + OFF_ZH);
    u16* Zl = (u16*)(ws + OFF_ZL);
    float* P0 = (float*)(ws + OFF_P0);
    float* P1 = P0 + (size_t)B_ * FOURH;
    int* ctrs = (int*)(ws + OFF_CTR);

    float* decoded = (float*)d_out;
    float* out_h = decoded + (size_t)TB_ * V_;
    float* out_c = out_h + 3 * (size_t)HB;

    hipMemsetAsync(ctrs, 0, 256 * sizeof(int), stream);
    gather_split_kernel<<<(TB_ * EPAD + 255) / 256, 256, 0, stream>>>(x, embW, Zh, Zl);
    init_state_kernel<<<(3 * HB + 255) / 256, 256, 0, stream>>>(h0, c0, Hhi, Hlo, Cst);

    dim3 gZ(FOURH / 128, TB_ / 192);  // 36 x 16

    /* layer 0: Zpre = emb @ Wi0^T, then recurrence */
    gemm_bias_kernel<<<gZ, 256, 0, stream>>>(Zh, Zl, EPAD, Wi0, E_, E_, (E_ + 31) / 32,
                                             nullptr, nullptr, Zpre, FOURH);
    recur_layer_kernel<<<RBLK, 256, 0, stream>>>(Wh0, bi0, bh0, Zpre, Hhi, Hlo, Cst,
                                                 P0, P1, ctrs, out_h, out_c);

    /* layer 1: Zpre = H0 @ Wi1^T, then recurrence */
    gemm_bias_kernel<<<gZ, 256, 0, stream>>>(Hhi + HB, Hlo + HB, H_, Wi1, H_, H_, H_ / 32,
                                             nullptr, nullptr, Zpre, FOURH);
    recur_layer_kernel<<<RBLK, 256, 0, stream>>>(Wh1, bi1, bh1, Zpre,
                                                 Hhi + LSTRIDE, Hlo + LSTRIDE, Cst + HB,
                                                 P0, P1, ctrs, out_h + HB, out_c + HB);

    /* layer 2: Zpre = H1 @ Wi2^T, then recurrence */
    gemm_bias_kernel<<<gZ, 256, 0, stream>>>(Hhi + LSTRIDE + HB, Hlo + LSTRIDE + HB, H_,
                                             Wi2, H_, H_, H_ / 32,
                                             nullptr, nullptr, Zpre, FOURH);
    recur_layer_kernel<<<RBLK, 256, 0, stream>>>(Wh2, bi2, bh2, Zpre,
                                                 Hhi + 2 * LSTRIDE, Hlo + 2 * LSTRIDE,
                                                 Cst + 2 * HB,
                                                 P0, P1, ctrs, out_h + 2 * HB, out_c + 2 * HB);

    /* decode: decoded = H2 @ Wdec^T + bdec */
    dim3 gD(V_ / 128, TB_ / 192);  // 250 x 16
    gemm_bias_kernel<<<gD, 256, 0, stream>>>(Hhi + (size_t)(2 * 65 + 1) * HB,
                                             Hlo + (size_t)(2 * 65 + 1) * HB, H_,
                                             Wdec, H_, H_, H_ / 32,
                                             bdec, nullptr, decoded, V_);
}

// Round 4
// 7509.801 us; speedup vs baseline: 1.1739x; 1.1739x over previous
//
#include <hip/hip_runtime.h>

typedef unsigned short u16;
typedef __attribute__((ext_vector_type(8))) short s16x8;
typedef __attribute__((ext_vector_type(4))) float f32x4;

#define T_ 64
#define B_ 48
#define H_ 1152
#define E_ 400
#define EPAD 416
#define V_ 32000
#define FOURH 4608
#define TB_ 3072
#define HB (B_*H_)            /* 55296 */
#define LSTRIDE (65*HB)       /* per-layer slot stride in H history */
#define RBLK 288              /* persistent recurrence blocks: 1 strip each, 16 groups x 18 */

/* ---- workspace byte offsets (all 256-aligned) ---- */
#define OFF_ZPRE  ((size_t)0)          /* f32 [3072][4608] = 56,623,104 B (reused per layer) */
#define OFF_HHI   ((size_t)56623104)   /* u16 [3][65][48][1152] = 21,565,440 B */
#define OFF_HLO   ((size_t)78188544)   /* u16 same */
#define OFF_ZH    ((size_t)100417536)  /* u16 [3072][416] = 2,555,904 B */
#define OFF_ZL    ((size_t)102973440)  /* u16 same */
#define OFF_CTR   ((size_t)116146176)  /* int[1024] barrier/counters */

__device__ __forceinline__ u16 f2bf(float x) {
    unsigned u = __float_as_uint(x);
    u += 0x7fffu + ((u >> 16) & 1u);      // round-to-nearest-even
    return (u16)(u >> 16);
}
__device__ __forceinline__ float bf2f(u16 h) {
    return __uint_as_float(((unsigned)h) << 16);
}
__device__ __forceinline__ void split8(const float* p, s16x8& hi, s16x8& lo) {
    f32x4 a = *(const f32x4*)(p);
    f32x4 b = *(const f32x4*)(p + 4);
    float v[8];
#pragma unroll
    for (int j = 0; j < 4; ++j) { v[j] = a[j]; v[j + 4] = b[j]; }
#pragma unroll
    for (int j = 0; j < 8; ++j) {
        u16 h = f2bf(v[j]);
        hi[j] = (short)h;
        lo[j] = (short)f2bf(v[j] - bf2f(h));
    }
}
__device__ __forceinline__ void split8r(f32x4 a, f32x4 b, s16x8& hi, s16x8& lo) {
    float v[8];
#pragma unroll
    for (int j = 0; j < 4; ++j) { v[j] = a[j]; v[j + 4] = b[j]; }
#pragma unroll
    for (int j = 0; j < 8; ++j) {
        u16 h = f2bf(v[j]);
        hi[j] = (short)h;
        lo[j] = (short)f2bf(v[j] - bf2f(h));
    }
}
__device__ __forceinline__ f32x4 mfma16(s16x8 a, s16x8 b, f32x4 c) {
    return __builtin_amdgcn_mfma_f32_16x16x32_bf16(a, b, c, 0, 0, 0);
}

/* ---- agent-coherent (sc1, cache-bypass) accessors for cross-block state. ---- */
__device__ __forceinline__ float ld_sc(const float* p) {
    return __hip_atomic_load(p, __ATOMIC_RELAXED, __HIP_MEMORY_SCOPE_AGENT);
}
__device__ __forceinline__ void st_sc16(u16* p, u16 v) {
    __hip_atomic_store(p, v, __ATOMIC_RELAXED, __HIP_MEMORY_SCOPE_AGENT);
}

/* ---------------- hierarchical-release grid barrier (288 = 16 groups x 18) ----
   ctrs int layout: gcnt[g] at g*16 (64B lines), root at 256, gen_root at 272,
   ggen[g] at 288+g*16. Epoch counters are monotonic across launches (ep0 param).
   Release chain: last arriver of a group resets gcnt, adds to root; last at root
   bumps gen_root; each group's releaser polls gen_root (<=16 pollers/line) then
   stores ggen[g]=epoch+1; other leaders poll their group line (<=17 pollers).
   No cache-wide flush anywhere: cross-block data uses sc1 ops, release =
   s_waitcnt vmcnt(0). gcnt reset is drained (vmcnt) before root-add, which
   precedes the ggen store -> no lost-arrival race. ---- */
__device__ __forceinline__ void grid_barrier2(int* ctrs, int epoch) {
    asm volatile("s_waitcnt vmcnt(0)" ::: "memory");  // release: sc1 stores at IF
    __syncthreads();
    if (threadIdx.x == 0) {
        const int grp = blockIdx.x & 15;
        int* gcnt = ctrs + grp * 16;
        int* root = ctrs + 256;
        int* genr = ctrs + 272;
        int* ggen = ctrs + 288 + grp * 16;
        const int gsz = RBLK / 16;   /* 18 */
        int old = __hip_atomic_fetch_add(gcnt, 1, __ATOMIC_RELAXED, __HIP_MEMORY_SCOPE_AGENT);
        if (old == gsz - 1) {
            __hip_atomic_store(gcnt, 0, __ATOMIC_RELAXED, __HIP_MEMORY_SCOPE_AGENT);
            asm volatile("s_waitcnt vmcnt(0)" ::: "memory");  // reset visible before root add
            int r = __hip_atomic_fetch_add(root, 1, __ATOMIC_RELAXED, __HIP_MEMORY_SCOPE_AGENT);
            if (r == 15) {
                __hip_atomic_store(root, 0, __ATOMIC_RELAXED, __HIP_MEMORY_SCOPE_AGENT);
                asm volatile("s_waitcnt vmcnt(0)" ::: "memory");
                __hip_atomic_fetch_add(genr, 1, __ATOMIC_RELAXED, __HIP_MEMORY_SCOPE_AGENT);
            } else {
                while (__hip_atomic_load(genr, __ATOMIC_RELAXED, __HIP_MEMORY_SCOPE_AGENT) <= epoch) {
                    __builtin_amdgcn_s_sleep(2);
                }
            }
            __hip_atomic_store(ggen, epoch + 1, __ATOMIC_RELAXED, __HIP_MEMORY_SCOPE_AGENT);
        } else {
            while (__hip_atomic_load(ggen, __ATOMIC_RELAXED, __HIP_MEMORY_SCOPE_AGENT) <= epoch) {
                __builtin_amdgcn_s_sleep(2);
            }
        }
    }
    __syncthreads();
}

/* ---------------- embedding gather + bf16 hi/lo split ---------------- */
__global__ void gather_split_kernel(const int* __restrict__ x, const float* __restrict__ embW,
                                    u16* __restrict__ Zh, u16* __restrict__ Zl) {
    int i = blockIdx.x * blockDim.x + threadIdx.x;
    const int total = TB_ * EPAD;
    if (i >= total) return;
    int tb = i / EPAD, k = i - tb * EPAD;
    float v = 0.f;
    if (k < E_) v = embW[(size_t)x[tb] * E_ + k];
    u16 h = f2bf(v);
    Zh[i] = h;
    Zl[i] = f2bf(v - bf2f(h));
}

/* ---------------- init h0 into history slot 0 ---------------- */
__global__ void init_state_kernel(const float* __restrict__ h0,
                                  u16* __restrict__ Hhi, u16* __restrict__ Hlo) {
    int i = blockIdx.x * blockDim.x + threadIdx.x;
    if (i >= 3 * HB) return;
    int l = i / HB, r = i - l * HB;
    float h = h0[i];
    u16 hh = f2bf(h);
    size_t idx = (size_t)l * LSTRIDE + r;   // slot 0 = t=-1 state
    Hhi[idx] = hh;
    Hlo[idx] = f2bf(h - bf2f(hh));
}

/* ---------------- generic big GEMM:  C[M,N] = A(hi/lo bf16)[M,K] * W(f32)[N,K]^T + bias
   1D grid with XCD-pinned panel swizzle: all 16 M-tiles of one N-panel run on the
   same XCD -> W panel read once into that XCD's L2 instead of streamed 4x. ---- */
__global__ __launch_bounds__(256, 2) void gemm_bias_kernel(
    const u16* __restrict__ Ahi, const u16* __restrict__ Alo, int lda,
    const float* __restrict__ W, int ldw, int kvalid, int ksteps, int npanels,
    const float* __restrict__ bias1,
    float* __restrict__ C, int ldc) {
    const int id = blockIdx.x;
    const int xcd = id & 7, slotb = id >> 3;
    const int panel = (slotb >> 4) * 8 + xcd;
    const int ytile = slotb & 15;
    if (panel >= npanels) return;
    const int lane = threadIdx.x & 63;
    const int wv = threadIdx.x >> 6;
    const int m16 = lane & 15, q = lane >> 4;
    const int mbase = ytile * 192 + wv * 48;
    const int nbase = panel * 128;

    f32x4 acc[8][3];
#pragma unroll
    for (int s8 = 0; s8 < 8; ++s8)
#pragma unroll
        for (int mt = 0; mt < 3; ++mt) acc[s8][mt] = (f32x4){0.f, 0.f, 0.f, 0.f};

    const u16* arow[3];
    const u16* alrow[3];
#pragma unroll
    for (int mt = 0; mt < 3; ++mt) {
        size_t m = (size_t)(mbase + mt * 16 + m16);
        arow[mt] = Ahi + m * lda + q * 8;
        alrow[mt] = Alo + m * lda + q * 8;
    }
    const float* wrow[8];
#pragma unroll
    for (int s8 = 0; s8 < 8; ++s8) {
        size_t n = (size_t)(nbase + s8 * 16 + m16);
        wrow[s8] = W + n * ldw + q * 8;
    }

    for (int ks = 0; ks < ksteps; ++ks) {
        int k = ks * 32;
        s16x8 ah[3], al[3];
#pragma unroll
        for (int mt = 0; mt < 3; ++mt) {
            ah[mt] = *(const s16x8*)(arow[mt] + k);
            al[mt] = *(const s16x8*)(alrow[mt] + k);
        }
        int kk = k + q * 8;
#pragma unroll
        for (int s8 = 0; s8 < 8; ++s8) {
            s16x8 wh, wl;
            if (kk + 8 <= kvalid) {
                split8(wrow[s8] + k, wh, wl);
            } else {
#pragma unroll
                for (int j = 0; j < 8; ++j) { wh[j] = 0; wl[j] = 0; }
            }
#pragma unroll
            for (int mt = 0; mt < 3; ++mt) {
                acc[s8][mt] = mfma16(ah[mt], wh, acc[s8][mt]);
                acc[s8][mt] = mfma16(ah[mt], wl, acc[s8][mt]);
                acc[s8][mt] = mfma16(al[mt], wh, acc[s8][mt]);
            }
        }
    }
    /* epilogue */
#pragma unroll
    for (int s8 = 0; s8 < 8; ++s8) {
        int n = nbase + s8 * 16 + m16;
        float bv = bias1 ? bias1[n] : 0.f;
#pragma unroll
        for (int mt = 0; mt < 3; ++mt)
#pragma unroll
            for (int r = 0; r < 4; ++r) {
                int m = mbase + mt * 16 + q * 4 + r;
                C[(size_t)m * ldc + n] = acc[s8][mt][r] + bv;
            }
    }
}

/* ---------------- persistent single-layer LSTM recurrence, fused gates --------
   One block = one strip of 16 logical columns n' (gate-interleaved mapping:
   n_nat = (n'&3)*H + (n'>>2)), 4 waves = 4 K-quarters. Per stage: quarter-GEMM,
   LDS combine, wave0 assembles gates in-register via quad shfl_xor, updates
   register-resident cell state, stores h (hi/lo) via sc1, ONE grid barrier.
   Weight slice per XCD = 2.65 MB -> L2-resident (no cache flushes ever). */
__global__ __launch_bounds__(256, 2) void recur_layer_kernel(
    const float* __restrict__ W,               /* Wh_l [4608][1152] natural order */
    const float* __restrict__ bi, const float* __restrict__ bh,
    const float* __restrict__ Zpre,            /* [64*48][4608] natural order */
    const float* __restrict__ c0l,             /* c0 + l*HB */
    u16* __restrict__ Hhi, u16* __restrict__ Hlo,  /* layer base [65][48][1152] */
    int* __restrict__ ctrs, int ep0,
    float* __restrict__ outh, float* __restrict__ outc) {
    __shared__ float lred[3][12][64];
    const int lane = threadIdx.x & 63;
    const int wv = threadIdx.x >> 6;           /* k-quarter 0..3 */
    const int m16 = lane & 15, q = lane >> 4;
    const int g = lane & 3;                    /* gate of this lane */
    const int strip = blockIdx.x;              /* 0..287 */
    const int nprime = strip * 16 + m16;
    const int j = nprime >> 2;                 /* hidden unit */
    const int n_nat = (nprime & 3) * H_ + j;   /* natural row of W / col of Zpre */
    const int koff = wv * 288;

    float biasn = 0.f;
    float creg0 = 0.f, creg1 = 0.f, creg2 = 0.f;
    if (wv == 0) {
        biasn = bi[n_nat] + bh[n_nat];
        creg0 = c0l[(0 * 16 + q * 4 + g) * H_ + j];
        creg1 = c0l[(1 * 16 + q * 4 + g) * H_ + j];
        creg2 = c0l[(2 * 16 + q * 4 + g) * H_ + j];
    }
    const float* wrow = W + (size_t)n_nat * H_ + koff + q * 8;

    for (int t = 0; t < 64; ++t) {
        /* issue zin early (wave0 only) — lands during the GEMM */
        float zin[3][4];
        if (wv == 0) {
            const float* zp = Zpre + (size_t)(t * B_) * FOURH + n_nat;
#pragma unroll
            for (int mt = 0; mt < 3; ++mt)
#pragma unroll
                for (int r = 0; r < 4; ++r)
                    zin[mt][r] = ld_sc(zp + (size_t)(mt * 16 + q * 4 + r) * FOURH);
        }
        /* ---- K-quarter GEMM: 9 steps of 32, W depth-2, A depth-2 pipeline ---- */
        f32x4 acc[3];
#pragma unroll
        for (int mt = 0; mt < 3; ++mt) acc[mt] = (f32x4){0.f, 0.f, 0.f, 0.f};
        const u16* arow[3];
        const u16* alrow[3];
#pragma unroll
        for (int mt = 0; mt < 3; ++mt) {
            size_t ro = (size_t)t * HB + (size_t)(mt * 16 + m16) * H_ + koff + q * 8;
            arow[mt] = Hhi + ro;
            alrow[mt] = Hlo + ro;
        }
        f32x4 w0A = *(const f32x4*)(wrow);
        f32x4 w0B = *(const f32x4*)(wrow + 4);
        f32x4 w1A = *(const f32x4*)(wrow + 32);
        f32x4 w1B = *(const f32x4*)(wrow + 36);
        s16x8 ah0[3], al0[3], ah1[3], al1[3];
#pragma unroll
        for (int mt = 0; mt < 3; ++mt) {
            ah0[mt] = *(const s16x8*)(arow[mt]);
            al0[mt] = *(const s16x8*)(alrow[mt]);
            ah1[mt] = *(const s16x8*)(arow[mt] + 32);
            al1[mt] = *(const s16x8*)(alrow[mt] + 32);
        }
#pragma unroll
        for (int ks = 0; ks < 9; ++ks) {
            const int kp2 = (ks + 2 <= 8) ? ks + 2 : 8;
            const int kn2 = kp2 * 32;
            f32x4 w2A = *(const f32x4*)(wrow + kn2);
            f32x4 w2B = *(const f32x4*)(wrow + kn2 + 4);
            s16x8 ah2[3], al2[3];
#pragma unroll
            for (int mt = 0; mt < 3; ++mt) {
                ah2[mt] = *(const s16x8*)(arow[mt] + kn2);
                al2[mt] = *(const s16x8*)(alrow[mt] + kn2);
            }
            s16x8 wh, wl;
            split8r(w0A, w0B, wh, wl);
#pragma unroll
            for (int mt = 0; mt < 3; ++mt) {
                acc[mt] = mfma16(ah0[mt], wh, acc[mt]);
                acc[mt] = mfma16(ah0[mt], wl, acc[mt]);
                acc[mt] = mfma16(al0[mt], wh, acc[mt]);
            }
            w0A = w1A; w0B = w1B; w1A = w2A; w1B = w2B;
#pragma unroll
            for (int mt = 0; mt < 3; ++mt) {
                ah0[mt] = ah1[mt]; al0[mt] = al1[mt];
                ah1[mt] = ah2[mt]; al1[mt] = al2[mt];
            }
        }
        /* ---- combine quarters in LDS ---- */
        if (wv > 0) {
#pragma unroll
            for (int mt = 0; mt < 3; ++mt)
#pragma unroll
                for (int r = 0; r < 4; ++r)
                    lred[wv - 1][mt * 4 + r][lane] = acc[mt][r];
        }
        __syncthreads();
        if (wv == 0) {
#pragma unroll
            for (int mt = 0; mt < 3; ++mt)
#pragma unroll
                for (int r = 0; r < 4; ++r)
                    acc[mt][r] += lred[0][mt * 4 + r][lane] + lred[1][mt * 4 + r][lane] +
                                  lred[2][mt * 4 + r][lane] + zin[mt][r] + biasn;
            /* ---- gates: quad shfl assembles i/f/o/g per (b, j) ---- */
#pragma unroll
            for (int mt = 0; mt < 3; ++mt) {
#pragma unroll
                for (int r = 0; r < 4; ++r) {
                    float y = acc[mt][r];
                    float y1 = __shfl_xor(y, 1);
                    float y2 = __shfl_xor(y, 2);
                    float y3 = __shfl_xor(y, 3);
                    if (r == g) {
                        float pi = (g == 0) ? y : (g == 1) ? y1 : (g == 2) ? y2 : y3;
                        float pf = (g == 0) ? y1 : (g == 1) ? y : (g == 2) ? y3 : y2;
                        float po = (g == 0) ? y2 : (g == 1) ? y3 : (g == 2) ? y : y1;
                        float pg_ = (g == 0) ? y3 : (g == 1) ? y2 : (g == 2) ? y1 : y;
                        float ig = 1.f / (1.f + expf(-pi));
                        float fg = 1.f / (1.f + expf(-pf));
                        float og = 1.f / (1.f + expf(-po));
                        float gg = tanhf(pg_);
                        float cprev = (mt == 0) ? creg0 : (mt == 1) ? creg1 : creg2;
                        float cn = fg * cprev + ig * gg;
                        float hn = og * tanhf(cn);
                        if (mt == 0) creg0 = cn; else if (mt == 1) creg1 = cn; else creg2 = cn;
                        u16 hh = f2bf(hn);
                        int b = mt * 16 + q * 4 + g;
                        size_t hidx = (size_t)(t + 1) * HB + (size_t)b * H_ + j;
                        st_sc16(Hhi + hidx, hh);
                        st_sc16(Hlo + hidx, f2bf(hn - bf2f(hh)));
                        if (t == 63) {
                            outh[b * H_ + j] = hn;
                            outc[b * H_ + j] = cn;
                        }
                    }
                }
            }
        }
        grid_barrier2(ctrs, ep0 + t);
    }
}

extern "C" void kernel_launch(void* const* d_in, const int* in_sizes, int n_in,
                              void* d_out, int out_size, void* d_ws, size_t ws_size,
                              hipStream_t stream) {
    (void)in_sizes; (void)n_in; (void)out_size; (void)ws_size;
    const int* x = (const int*)d_in[0];
    const float* h0 = (const float*)d_in[1];
    const float* c0 = (const float*)d_in[2];
    const float* embW = (const float*)d_in[3];
    const float* Wi0 = (const float*)d_in[4];
    const float* bi0 = (const float*)d_in[5];
    const float* Wh0 = (const float*)d_in[6];
    const float* bh0 = (const float*)d_in[7];
    const float* Wi1 = (const float*)d_in[8];
    const float* bi1 = (const float*)d_in[9];
    const float* Wh1 = (const float*)d_in[10];
    const float* bh1 = (const float*)d_in[11];
    const float* Wi2 = (const float*)d_in[12];
    const float* bi2 = (const float*)d_in[13];
    const float* Wh2 = (const float*)d_in[14];
    const float* bh2 = (const float*)d_in[15];
    const float* Wdec = (const float*)d_in[16];
    const float* bdec = (const float*)d_in[17];

    char* ws = (char*)d_ws;
    float* Zpre = (float*)(ws + OFF_ZPRE);
    u16* Hhi = (u16*)(ws + OFF_HHI);
    u16* Hlo = (u16*)(ws + OFF_HLO);
    u16* Zh = (u16*)(ws + OFF_ZH);
    u16* Zl = (u16*)(ws + OFF_ZL);
    int* ctrs = (int*)(ws + OFF_CTR);

    float* decoded = (float*)d_out;
    float* out_h = decoded + (size_t)TB_ * V_;
    float* out_c = out_h + 3 * (size_t)HB;

    hipMemsetAsync(ctrs, 0, 4096, stream);
    gather_split_kernel<<<(TB_ * EPAD + 255) / 256, 256, 0, stream>>>(x, embW, Zh, Zl);
    init_state_kernel<<<(3 * HB + 255) / 256, 256, 0, stream>>>(h0, Hhi, Hlo);

    const int gZ = 8 * ((36 + 7) / 8) * 16;   /* 640 blocks, 36 panels */
    const int gD = 8 * ((250 + 7) / 8) * 16;  /* 4096 blocks, 250 panels */

    /* layer 0 */
    gemm_bias_kernel<<<gZ, 256, 0, stream>>>(Zh, Zl, EPAD, Wi0, E_, E_, (E_ + 31) / 32, 36,
                                             nullptr, Zpre, FOURH);
    recur_layer_kernel<<<RBLK, 256, 0, stream>>>(Wh0, bi0, bh0, Zpre, c0,
                                                 Hhi, Hlo, ctrs, 0, out_h, out_c);
    /* layer 1 */
    gemm_bias_kernel<<<gZ, 256, 0, stream>>>(Hhi + HB, Hlo + HB, H_, Wi1, H_, H_, H_ / 32, 36,
                                             nullptr, Zpre, FOURH);
    recur_layer_kernel<<<RBLK, 256, 0, stream>>>(Wh1, bi1, bh1, Zpre, c0 + HB,
                                                 Hhi + LSTRIDE, Hlo + LSTRIDE, ctrs, 64,
                                                 out_h + HB, out_c + HB);
    /* layer 2 */
    gemm_bias_kernel<<<gZ, 256, 0, stream>>>(Hhi + LSTRIDE + HB, Hlo + LSTRIDE + HB, H_,
                                             Wi2, H_, H_, H_ / 32, 36,
                                             nullptr, Zpre, FOURH);
    recur_layer_kernel<<<RBLK, 256, 0, stream>>>(Wh2, bi2, bh2, Zpre, c0 + 2 * HB,
                                                 Hhi + 2 * LSTRIDE, Hlo + 2 * LSTRIDE, ctrs, 128,
                                                 out_h + 2 * HB, out_c + 2 * HB);

    /* decode: decoded = H2(slots 1..64) @ Wdec^T + bdec */
    gemm_bias_kernel<<<gD, 256, 0, stream>>>(Hhi + (size_t)(2 * 65 + 1) * HB,
                                             Hlo + (size_t)(2 * 65 + 1) * HB, H_,
                                             Wdec, H_, H_, H_ / 32, 250,
                                             bdec, decoded, V_);
}